// Round 16
// baseline (589.234 us; speedup 1.0000x reference)
//
#include <hip/hip_runtime.h>
#include <cstdint>
#include <cstddef>

#define T_TOKENS 4096
#define D_MODEL  1024
#define N_EXP    8
#define TOP_K    4
#define H_EXP    1024
#define SH_HID   2048
#define TK       (T_TOKENS*TOP_K)

typedef __bf16 bf16x8 __attribute__((ext_vector_type(8)));
typedef __bf16 bf16x4 __attribute__((ext_vector_type(4)));
typedef float  f32x4  __attribute__((ext_vector_type(4)));

__device__ __forceinline__ float silu_f(float x) {
    return x / (1.0f + expf(-x));
}

// =========================================================================
// gemm_sp (proven): fp32 A, fp32 W, in-loop split conversion.
// NT=3: 6 MFMA terms, fp32-grade — router-feeding prefix (+ fallback path).
// =========================================================================
template<int NT, bool SEG, bool GATHER, bool GLU>
__global__ __launch_bounds__(256)
void gemm_sp(const float* __restrict__ A, int lda,
             const float* __restrict__ W1, const float* __restrict__ W3,
             int64_t w_estride, int ldw,
             const float* __restrict__ bias1, const float* __restrict__ bias2,
             float* __restrict__ C, __bf16* __restrict__ Cb1, int ldc,
             int M, int Kd,
             const int* __restrict__ seg_off,
             const int* __restrict__ gather)
{
    constexpr int BM = 128, BN = 128, BK = 32;
    __shared__ __bf16 Asl[NT][BM * BK];
    __shared__ __bf16 Bsl[NT][BN * BK];

    int m0, m1, e = 0;
    if (SEG) {
        e = blockIdx.z;
        int s0 = seg_off[e], s1 = seg_off[e + 1];
        m0 = s0 + blockIdx.y * BM;
        if (m0 >= s1) return;
        m1 = (m0 + BM < s1) ? (m0 + BM) : s1;
    } else {
        m0 = blockIdx.y * BM;
        m1 = (m0 + BM < M) ? (m0 + BM) : M;
    }
    const int n0 = blockIdx.x * BN;

    const int tid  = threadIdx.x;
    const int lane = tid & 63;
    const int w    = tid >> 6;
    const int wm   = w >> 1, wn = w & 1;
    const int fr   = lane & 15, fq = lane >> 4;

    const float* aP[4]; int aR[4], aQ[4];
#pragma unroll
    for (int i = 0; i < 4; ++i) {
        int Li = tid + 256 * i;
        int r = Li >> 3, q = Li & 7;
        aR[i] = r; aQ[i] = q;
        int grow = m0 + r;
        if (grow > m1 - 1) grow = m1 - 1;
        if (GATHER) grow = gather[grow];
        aP[i] = A + (int64_t)grow * lda + q * 4;
    }

    const int bn  = tid & 127;
    const int bkh = tid >> 7;
    const float* Wsrc; int wcol;
    if (GLU) {
        int cl = n0 + bn;
        int B  = cl >> 4;
        Wsrc = (B & 1) ? W3 : W1;
        wcol = ((B >> 1) << 4) | (cl & 15);
    } else {
        Wsrc = W1; wcol = n0 + bn;
    }
    const float* Wb = Wsrc + (int64_t)e * w_estride + (int64_t)(bkh * 16) * ldw + wcol;

    f32x4 zero4 = {0.f, 0.f, 0.f, 0.f};
    f32x4 acc[4][4];
#pragma unroll
    for (int i = 0; i < 4; ++i)
#pragma unroll
        for (int j = 0; j < 4; ++j) acc[i][j] = zero4;

    float4 av[4];
    float  wv[16];

#define GLOADS(K0)                                                         \
    do {                                                                   \
        _Pragma("unroll")                                                  \
        for (int i = 0; i < 4; ++i)                                        \
            av[i] = *reinterpret_cast<const float4*>(aP[i] + (K0));        \
        _Pragma("unroll")                                                  \
        for (int j = 0; j < 16; ++j)                                       \
            wv[j] = Wb[(int64_t)((K0) + j) * ldw];                         \
    } while (0)

    const int nk = Kd / BK;
    GLOADS(0);

    for (int ks = 0; ks < nk; ++ks) {
        bf16x4 pa[NT][4];
        bf16x4 pw[NT][4];
#pragma unroll
        for (int i = 0; i < 4; ++i) {
            float vv[4] = {av[i].x, av[i].y, av[i].z, av[i].w};
#pragma unroll
            for (int t = 0; t < 4; ++t) {
                float v = vv[t];
                __bf16 h = (__bf16)v;
                pa[0][i][t] = h;
                if (NT >= 2) {
                    float r = v - (float)h;
                    if (NT == 2) {
                        pa[1][i][t] = (__bf16)r;
                    } else {
                        __bf16 m = (__bf16)r;
                        pa[1][i][t] = m;
                        pa[2][i][t] = (__bf16)(r - (float)m);
                    }
                }
            }
        }
#pragma unroll
        for (int qd = 0; qd < 4; ++qd) {
#pragma unroll
            for (int t = 0; t < 4; ++t) {
                float v = wv[qd * 4 + t];
                __bf16 h = (__bf16)v;
                pw[0][qd][t] = h;
                if (NT >= 2) {
                    float r = v - (float)h;
                    if (NT == 2) {
                        pw[1][qd][t] = (__bf16)r;
                    } else {
                        __bf16 m = (__bf16)r;
                        pw[1][qd][t] = m;
                        pw[2][qd][t] = (__bf16)(r - (float)m);
                    }
                }
            }
        }

        __syncthreads();
#pragma unroll
        for (int i = 0; i < 4; ++i) {
            int r = aR[i], q = aQ[i];
            int c = (q >> 1) ^ ((r >> 1) & 3);
            int idx = r * BK + c * 8 + (q & 1) * 4;
#pragma unroll
            for (int p = 0; p < NT; ++p)
                *reinterpret_cast<bf16x4*>(&Asl[p][idx]) = pa[p][i];
        }
#pragma unroll
        for (int qd = 0; qd < 4; ++qd) {
            int q32 = bkh * 4 + qd;
            int c = (q32 >> 1) ^ ((bn >> 1) & 3);
            int idx = bn * BK + c * 8 + (q32 & 1) * 4;
#pragma unroll
            for (int p = 0; p < NT; ++p)
                *reinterpret_cast<bf16x4*>(&Bsl[p][idx]) = pw[p][qd];
        }

        if (ks + 1 < nk) GLOADS((ks + 1) * BK);
        __syncthreads();

        bf16x8 bfr[NT][4];
#pragma unroll
        for (int p = 0; p < NT; ++p)
#pragma unroll
            for (int j = 0; j < 4; ++j) {
                int rown = wn * 64 + j * 16 + fr;
                int c = fq ^ ((rown >> 1) & 3);
                bfr[p][j] = *reinterpret_cast<const bf16x8*>(&Bsl[p][rown * BK + c * 8]);
            }
#pragma unroll
        for (int im = 0; im < 4; ++im) {
            bf16x8 af[NT];
            int rowm = wm * 64 + im * 16 + fr;
            int c = fq ^ ((rowm >> 1) & 3);
#pragma unroll
            for (int p = 0; p < NT; ++p)
                af[p] = *reinterpret_cast<const bf16x8*>(&Asl[p][rowm * BK + c * 8]);
#pragma unroll
            for (int jn = 0; jn < 4; ++jn) {
                f32x4 a = acc[im][jn];
                a = __builtin_amdgcn_mfma_f32_16x16x32_bf16(af[0], bfr[0][jn], a, 0, 0, 0);
                if (NT >= 2) {
                    a = __builtin_amdgcn_mfma_f32_16x16x32_bf16(af[0], bfr[1][jn], a, 0, 0, 0);
                    a = __builtin_amdgcn_mfma_f32_16x16x32_bf16(af[1], bfr[0][jn], a, 0, 0, 0);
                }
                if (NT == 3) {
                    a = __builtin_amdgcn_mfma_f32_16x16x32_bf16(af[1], bfr[1][jn], a, 0, 0, 0);
                    a = __builtin_amdgcn_mfma_f32_16x16x32_bf16(af[0], bfr[2][jn], a, 0, 0, 0);
                    a = __builtin_amdgcn_mfma_f32_16x16x32_bf16(af[2], bfr[0][jn], a, 0, 0, 0);
                }
                acc[im][jn] = a;
            }
        }
    }
#undef GLOADS

    if (GLU) {
#pragma unroll
        for (int jn = 0; jn < 4; jn += 2) {
            int gcol = (n0 >> 1) + wn * 32 + (jn >> 1) * 16 + fr;
            float bv1 = bias1 ? bias1[gcol] : 0.f;
            float bv2 = bias2 ? bias2[gcol] : 0.f;
#pragma unroll
            for (int im = 0; im < 4; ++im) {
                f32x4 v1 = acc[im][jn];
                f32x4 v2 = acc[im][jn + 1];
#pragma unroll
                for (int r = 0; r < 4; ++r) {
                    int grow = m0 + wm * 64 + im * 16 + fq * 4 + r;
                    if (grow < m1) {
                        float val = silu_f(v1[r] + bv1) * (v2[r] + bv2);
                        int64_t o = (int64_t)grow * ldc + gcol;
                        C[o] = val;
                        if (Cb1) Cb1[o] = (__bf16)val;
                    }
                }
            }
        }
    } else {
#pragma unroll
        for (int jn = 0; jn < 4; ++jn) {
            int col = n0 + wn * 64 + jn * 16 + fr;
            float bv = bias1 ? bias1[col] : 0.f;
#pragma unroll
            for (int im = 0; im < 4; ++im) {
                f32x4 v = acc[im][jn];
#pragma unroll
                for (int r = 0; r < 4; ++r) {
                    int grow = m0 + wm * 64 + im * 16 + fq * 4 + r;
                    if (grow < m1)
                        C[(int64_t)grow * ldc + col] = v[r] + bv;
                }
            }
        }
    }
}

// =========================================================================
// gemm_b64: 128x128, 4 waves, 64x64 wave tile, BK=64 (half the barriers of
// BK=32). LDS layout = TWO back-to-back BK=32 half-tiles [2][128][32], each
// with the proven conflict-free 2-bit swizzle (c ^ ((r>>1)&3)); half-tile 1
// sits at a FIXED +4096-element offset, so the second frag read is a
// compile-time ds_read offset (round 15's row-dependent 3-bit XOR added
// hot-loop VALU/VGPR and regressed). Write/read permutations match ->
// bit-identical. W pre-transposed bf16 [N][K] (ldw = Kd).
// =========================================================================
template<bool SEG, bool GATHER, bool GLU, bool EMITB>
__global__ __launch_bounds__(256)
void gemm_b64(const __bf16* __restrict__ A, int lda,
              const __bf16* __restrict__ W1, const __bf16* __restrict__ W3,
              int64_t w_estride, int ldw,
              const float* __restrict__ bias1, const float* __restrict__ bias2,
              float* __restrict__ C, __bf16* __restrict__ Cb, int ldc,
              int M, int Kd,
              const int* __restrict__ seg_off,
              const int* __restrict__ gather)
{
    constexpr int BK = 64;
    constexpr int HALF = 128 * 32;     // elements per half-tile
    __shared__ __bf16 Asl[128 * BK];   // 16 KB: [2][128][32]
    __shared__ __bf16 Bsl[128 * BK];   // 16 KB: [2][128][32]

    int m0, m1, e = 0;
    if (SEG) {
        e = blockIdx.z;
        int s0 = seg_off[e], s1 = seg_off[e + 1];
        m0 = s0 + blockIdx.y * 128;
        if (m0 >= s1) return;
        m1 = (m0 + 128 < s1) ? (m0 + 128) : s1;
    } else {
        m0 = blockIdx.y * 128;
        m1 = (m0 + 128 < M) ? (m0 + 128) : M;
    }
    const int n0 = blockIdx.x * 128;

    const int tid  = threadIdx.x;
    const int lane = tid & 63;
    const int w    = tid >> 6;
    const int wm   = w >> 1, wn = w & 1;
    const int fr   = lane & 15, fq = lane >> 4;

    // ---- A staging: 4 x bf16x8 (128 rows x 8 chunks / 256 threads)
    int aWr[4]; const __bf16* Ab[4];
#pragma unroll
    for (int i = 0; i < 4; ++i) {
        int L = tid + 256 * i;
        int r = L >> 3, ch = L & 7;
        int half = ch >> 2, c32 = ch & 3;
        aWr[i] = half * HALF + r * 32 + (c32 ^ ((r >> 1) & 3)) * 8;
        int grow = m0 + r;
        if (grow > m1 - 1) grow = m1 - 1;
        if (GATHER) grow = gather[grow];
        Ab[i] = A + (int64_t)grow * lda + ch * 8;
    }

    // ---- W staging: 4 x bf16x8 (128 W^T rows x 8 chunks / 256 threads)
    int wR[4]; const __bf16* Wt[4];
#pragma unroll
    for (int i = 0; i < 4; ++i) {
        int L = tid + 256 * i;
        int nl = L >> 3, ch = L & 7;
        int half = ch >> 2, c32 = ch & 3;
        wR[i] = half * HALF + nl * 32 + (c32 ^ ((nl >> 1) & 3)) * 8;
        int cl = n0 + nl;
        const __bf16* base; int srcrow;
        if (GLU) {
            int B = cl >> 4;
            base = (B & 1) ? W3 : W1;
            srcrow = ((B >> 1) << 4) | (cl & 15);
        } else {
            base = W1; srcrow = cl;
        }
        Wt[i] = base + (int64_t)e * w_estride + (int64_t)srcrow * ldw + ch * 8;
    }

    f32x4 zero4 = {0.f, 0.f, 0.f, 0.f};
    f32x4 acc[4][4];
#pragma unroll
    for (int i = 0; i < 4; ++i)
#pragma unroll
        for (int j = 0; j < 4; ++j) acc[i][j] = zero4;

    bf16x8 areg[4];
    bf16x8 wreg[4];

#define GLOADS(K0)                                                          \
    do {                                                                    \
        _Pragma("unroll")                                                   \
        for (int i = 0; i < 4; ++i) {                                       \
            areg[i] = *reinterpret_cast<const bf16x8*>(Ab[i] + (K0));       \
            wreg[i] = *reinterpret_cast<const bf16x8*>(Wt[i] + (K0));       \
        }                                                                   \
    } while (0)

    const int nk = Kd / BK;
    GLOADS(0);

    for (int ks = 0; ks < nk; ++ks) {
        __syncthreads();
#pragma unroll
        for (int i = 0; i < 4; ++i) {
            *reinterpret_cast<bf16x8*>(&Asl[aWr[i]]) = areg[i];
            *reinterpret_cast<bf16x8*>(&Bsl[wR[i]]) = wreg[i];
        }
        if (ks + 1 < nk) GLOADS((ks + 1) * BK);
        __syncthreads();

        bf16x8 bfr[2][4];
#pragma unroll
        for (int j = 0; j < 4; ++j) {
            int rown = wn * 64 + j * 16 + fr;
            int c = fq ^ ((rown >> 1) & 3);
            int base = rown * 32 + c * 8;
            bfr[0][j] = *reinterpret_cast<const bf16x8*>(&Bsl[base]);
            bfr[1][j] = *reinterpret_cast<const bf16x8*>(&Bsl[HALF + base]);
        }
#pragma unroll
        for (int im = 0; im < 4; ++im) {
            int rowm = wm * 64 + im * 16 + fr;
            int c = fq ^ ((rowm >> 1) & 3);
            int base = rowm * 32 + c * 8;
            bf16x8 af0 = *reinterpret_cast<const bf16x8*>(&Asl[base]);
            bf16x8 af1 = *reinterpret_cast<const bf16x8*>(&Asl[HALF + base]);
#pragma unroll
            for (int jn = 0; jn < 4; ++jn) {
                f32x4 a = acc[im][jn];
                a = __builtin_amdgcn_mfma_f32_16x16x32_bf16(af0, bfr[0][jn], a, 0, 0, 0);
                a = __builtin_amdgcn_mfma_f32_16x16x32_bf16(af1, bfr[1][jn], a, 0, 0, 0);
                acc[im][jn] = a;
            }
        }
    }
#undef GLOADS

    if (GLU) {
#pragma unroll
        for (int jn = 0; jn < 4; jn += 2) {
            int gcol = (n0 >> 1) + wn * 32 + (jn >> 1) * 16 + fr;
            float bv1 = bias1 ? bias1[gcol] : 0.f;
            float bv2 = bias2 ? bias2[gcol] : 0.f;
#pragma unroll
            for (int im = 0; im < 4; ++im) {
                f32x4 v1 = acc[im][jn];
                f32x4 v2 = acc[im][jn + 1];
#pragma unroll
                for (int r = 0; r < 4; ++r) {
                    int grow = m0 + wm * 64 + im * 16 + fq * 4 + r;
                    if (grow < m1) {
                        float val = silu_f(v1[r] + bv1) * (v2[r] + bv2);
                        int64_t o = (int64_t)grow * ldc + gcol;
                        if (EMITB) Cb[o] = (__bf16)val;
                        else       C[o]  = val;
                    }
                }
            }
        }
    } else {
#pragma unroll
        for (int jn = 0; jn < 4; ++jn) {
            int col = n0 + wn * 64 + jn * 16 + fr;
            float bv = bias1 ? bias1[col] : 0.f;
#pragma unroll
            for (int im = 0; im < 4; ++im) {
                f32x4 v = acc[im][jn];
#pragma unroll
                for (int r = 0; r < 4; ++r) {
                    int grow = m0 + wm * 64 + im * 16 + fq * 4 + r;
                    if (grow < m1) {
                        int64_t o = (int64_t)grow * ldc + col;
                        if (EMITB) Cb[o] = (__bf16)(v[r] + bv);
                        else       C[o]  = v[r] + bv;
                    }
                }
            }
        }
    }
}

// =========================================================================
// gemm_bb (round-10 proven, WBF=false strided path): fallback only.
// =========================================================================
template<bool WBF, bool SEG, bool GATHER, bool GLU, bool EMITB>
__global__ __launch_bounds__(256)
void gemm_bb(const __bf16* __restrict__ A, int lda,
             const void* __restrict__ W1v, const void* __restrict__ W3v,
             int64_t w_estride, int ldw,
             const float* __restrict__ bias1, const float* __restrict__ bias2,
             float* __restrict__ C, __bf16* __restrict__ Cb, int ldc,
             int M, int Kd,
             const int* __restrict__ seg_off,
             const int* __restrict__ gather)
{
    constexpr int BK = 32;
    __shared__ __bf16 Asl[128 * BK];
    __shared__ __bf16 Bsl[128 * BK];

    int m0, m1, e = 0;
    if (SEG) {
        e = blockIdx.z;
        int s0 = seg_off[e], s1 = seg_off[e + 1];
        m0 = s0 + blockIdx.y * 128;
        if (m0 >= s1) return;
        m1 = (m0 + 128 < s1) ? (m0 + 128) : s1;
    } else {
        m0 = blockIdx.y * 128;
        m1 = (m0 + 128 < M) ? (m0 + 128) : M;
    }
    const int n0 = blockIdx.x * 128;

    const int tid  = threadIdx.x;
    const int lane = tid & 63;
    const int w    = tid >> 6;
    const int wm   = w >> 1, wn = w & 1;
    const int fr   = lane & 15, fq = lane >> 4;

    int aWr[2]; const __bf16* Ab[2];
#pragma unroll
    for (int i = 0; i < 2; ++i) {
        int L = tid + 256 * i;
        int r = L >> 2, ch = L & 3;
        aWr[i] = r * BK + (ch ^ ((r >> 1) & 3)) * 8;
        int grow = m0 + r;
        if (grow > m1 - 1) grow = m1 - 1;
        if (GATHER) grow = gather[grow];
        Ab[i] = A + (int64_t)grow * lda + ch * 8;
    }

    int wR[2]; const __bf16* Wt[2];
    const float* Wbf = nullptr;
    int wWrS[2];
    if (WBF) {
#pragma unroll
        for (int i = 0; i < 2; ++i) {
            int L = tid + 256 * i;
            int nl = L >> 2, ch = L & 3;
            wR[i] = nl * BK + (ch ^ ((nl >> 1) & 3)) * 8;
            int cl = n0 + nl;
            const __bf16* base;
            int srcrow;
            if (GLU) {
                int B = cl >> 4;
                base = (const __bf16*)((B & 1) ? W3v : W1v);
                srcrow = ((B >> 1) << 4) | (cl & 15);
            } else {
                base = (const __bf16*)W1v;
                srcrow = cl;
            }
            Wt[i] = base + (int64_t)e * w_estride + (int64_t)srcrow * ldw + ch * 8;
        }
    } else {
        const int bn  = tid & 127;
        const int bkh = tid >> 7;
        int wcol; const void* Wsel;
        if (GLU) {
            int cl = n0 + bn;
            int B  = cl >> 4;
            Wsel = (B & 1) ? W3v : W1v;
            wcol = ((B >> 1) << 4) | (cl & 15);
        } else {
            Wsel = W1v; wcol = n0 + bn;
        }
        Wbf = (const float*)Wsel + (int64_t)e * w_estride + (int64_t)(bkh * 16) * ldw + wcol;
#pragma unroll
        for (int c = 0; c < 2; ++c)
            wWrS[c] = bn * BK + ((bkh * 2 + c) ^ ((bn >> 1) & 3)) * 8;
    }

    f32x4 zero4 = {0.f, 0.f, 0.f, 0.f};
    f32x4 acc[4][4];
#pragma unroll
    for (int i = 0; i < 4; ++i)
#pragma unroll
        for (int j = 0; j < 4; ++j) acc[i][j] = zero4;

    bf16x8 areg[2];
    bf16x8 wreg[2];

#define GLOADS(K0)                                                          \
    do {                                                                    \
        areg[0] = *reinterpret_cast<const bf16x8*>(Ab[0] + (K0));           \
        areg[1] = *reinterpret_cast<const bf16x8*>(Ab[1] + (K0));           \
        if (WBF) {                                                          \
            wreg[0] = *reinterpret_cast<const bf16x8*>(Wt[0] + (K0));       \
            wreg[1] = *reinterpret_cast<const bf16x8*>(Wt[1] + (K0));       \
        } else {                                                            \
            _Pragma("unroll")                                               \
            for (int j = 0; j < 16; ++j)                                    \
                wreg[j >> 3][j & 7] = (__bf16)Wbf[(int64_t)((K0) + j) * ldw]; \
        }                                                                   \
    } while (0)

    const int nk = Kd / BK;
    GLOADS(0);

    for (int ks = 0; ks < nk; ++ks) {
        __syncthreads();
        *reinterpret_cast<bf16x8*>(&Asl[aWr[0]]) = areg[0];
        *reinterpret_cast<bf16x8*>(&Asl[aWr[1]]) = areg[1];
        if (WBF) {
            *reinterpret_cast<bf16x8*>(&Bsl[wR[0]]) = wreg[0];
            *reinterpret_cast<bf16x8*>(&Bsl[wR[1]]) = wreg[1];
        } else {
            *reinterpret_cast<bf16x8*>(&Bsl[wWrS[0]]) = wreg[0];
            *reinterpret_cast<bf16x8*>(&Bsl[wWrS[1]]) = wreg[1];
        }
        if (ks + 1 < nk) GLOADS((ks + 1) * BK);
        __syncthreads();

        bf16x8 bfr[4];
#pragma unroll
        for (int j = 0; j < 4; ++j) {
            int rown = wn * 64 + j * 16 + fr;
            int c = fq ^ ((rown >> 1) & 3);
            bfr[j] = *reinterpret_cast<const bf16x8*>(&Bsl[rown * BK + c * 8]);
        }
#pragma unroll
        for (int im = 0; im < 4; ++im) {
            int rowm = wm * 64 + im * 16 + fr;
            int c = fq ^ ((rowm >> 1) & 3);
            bf16x8 af = *reinterpret_cast<const bf16x8*>(&Asl[rowm * BK + c * 8]);
#pragma unroll
            for (int jn = 0; jn < 4; ++jn)
                acc[im][jn] = __builtin_amdgcn_mfma_f32_16x16x32_bf16(af, bfr[jn], acc[im][jn], 0, 0, 0);
        }
    }
#undef GLOADS

    if (GLU) {
#pragma unroll
        for (int jn = 0; jn < 4; jn += 2) {
            int gcol = (n0 >> 1) + wn * 32 + (jn >> 1) * 16 + fr;
            float bv1 = bias1 ? bias1[gcol] : 0.f;
            float bv2 = bias2 ? bias2[gcol] : 0.f;
#pragma unroll
            for (int im = 0; im < 4; ++im) {
                f32x4 v1 = acc[im][jn];
                f32x4 v2 = acc[im][jn + 1];
#pragma unroll
                for (int r = 0; r < 4; ++r) {
                    int grow = m0 + wm * 64 + im * 16 + fq * 4 + r;
                    if (grow < m1) {
                        float val = silu_f(v1[r] + bv1) * (v2[r] + bv2);
                        int64_t o = (int64_t)grow * ldc + gcol;
                        if (EMITB) Cb[o] = (__bf16)val;
                        else       C[o]  = val;
                    }
                }
            }
        }
    } else {
#pragma unroll
        for (int jn = 0; jn < 4; ++jn) {
            int col = n0 + wn * 64 + jn * 16 + fr;
            float bv = bias1 ? bias1[col] : 0.f;
#pragma unroll
            for (int im = 0; im < 4; ++im) {
                f32x4 v = acc[im][jn];
#pragma unroll
                for (int r = 0; r < 4; ++r) {
                    int grow = m0 + wm * 64 + im * 16 + fq * 4 + r;
                    if (grow < m1) {
                        int64_t o = (int64_t)grow * ldc + col;
                        if (EMITB) Cb[o] = (__bf16)(v[r] + bv);
                        else       C[o]  = v[r] + bv;
                    }
                }
            }
        }
    }
}

// -------------------------------------------------------------------------
// Transpose + fp32->bf16 (RNE): src fp32 [R][C] -> dst bf16 [C][R].
// -------------------------------------------------------------------------
__global__ __launch_bounds__(256)
void f2bT(const float* __restrict__ src, __bf16* __restrict__ dst, int R, int C)
{
    __shared__ float t[32][33];
    const int64_t eoff = (int64_t)blockIdx.z * R * C;
    src += eoff; dst += eoff;
    const int c0 = blockIdx.x * 32, r0 = blockIdx.y * 32;
    const int tx = threadIdx.x & 31, ty = threadIdx.x >> 5;
#pragma unroll
    for (int i = 0; i < 4; ++i) {
        int r = r0 + ty + i * 8;
        t[ty + i * 8][tx] = src[(int64_t)r * C + c0 + tx];
    }
    __syncthreads();
#pragma unroll
    for (int i = 0; i < 4; ++i) {
        int c = c0 + ty + i * 8;
        dst[(int64_t)c * R + r0 + tx] = (__bf16)t[tx][ty + i * 8];
    }
}

// -------------------------------------------------------------------------
// Router (atomic-free ballot rank/scan, proven)
// -------------------------------------------------------------------------
__global__ __launch_bounds__(256)
void router_logits(const float* __restrict__ h1, const float* __restrict__ gw,
                   int* __restrict__ topi, float* __restrict__ topw,
                   unsigned char* __restrict__ emask)
{
    const int wave = threadIdx.x >> 6, lane = threadIdx.x & 63;
    const int t = blockIdx.x * 4 + wave;
    const float* x = h1 + (int64_t)t * D_MODEL;
    float part[N_EXP];
#pragma unroll
    for (int e = 0; e < N_EXP; ++e) part[e] = 0.f;
#pragma unroll 4
    for (int i = 0; i < D_MODEL / 64; ++i) {
        int d = lane + 64 * i;
        float xv = x[d];
#pragma unroll
        for (int e = 0; e < N_EXP; ++e)
            part[e] = fmaf(xv, gw[e * D_MODEL + d], part[e]);
    }
#pragma unroll
    for (int m = 32; m > 0; m >>= 1)
#pragma unroll
        for (int e = 0; e < N_EXP; ++e)
            part[e] += __shfl_xor(part[e], m, 64);

    if (lane == 0) {
        float p[N_EXP];
        float mx = -1e30f;
#pragma unroll
        for (int e = 0; e < N_EXP; ++e) mx = part[e] > mx ? part[e] : mx;
        float z = 0.f;
#pragma unroll
        for (int e = 0; e < N_EXP; ++e) { p[e] = expf(part[e] - mx); z += p[e]; }
#pragma unroll
        for (int e = 0; e < N_EXP; ++e) p[e] /= z;
        bool used[N_EXP];
#pragma unroll
        for (int e = 0; e < N_EXP; ++e) used[e] = false;
        int sel[TOP_K]; float sv[TOP_K]; float wsum = 0.f;
        unsigned m8 = 0;
        for (int k = 0; k < TOP_K; ++k) {
            int best = 0; float bvv = -1.f;
            for (int e = 0; e < N_EXP; ++e)
                if (!used[e] && p[e] > bvv) { bvv = p[e]; best = e; }
            used[best] = true; sel[k] = best; sv[k] = bvv; wsum += bvv;
            m8 |= 1u << best;
        }
        for (int k = 0; k < TOP_K; ++k) {
            int idx = t * TOP_K + k;
            topi[idx] = sel[k];
            topw[idx] = sv[k] / wsum;
        }
        emask[t] = (unsigned char)m8;
    }
}

__global__ __launch_bounds__(256)
void rank_local(const unsigned char* __restrict__ emask,
                const int* __restrict__ topi,
                int* __restrict__ pose, int* __restrict__ bh)
{
    const int b = blockIdx.x;
    const int t = b * 256 + threadIdx.x;
    const int wave = threadIdx.x >> 6, lane = threadIdx.x & 63;
    const unsigned m8 = emask[t];

    __shared__ int wcnt[4][N_EXP];
    __shared__ int wbase[4][N_EXP];
    int lrank[N_EXP];
#pragma unroll
    for (int e = 0; e < N_EXP; ++e) {
        unsigned long long bal = __ballot((m8 >> e) & 1u);
        lrank[e] = __popcll(bal & ((1ull << lane) - 1ull));
        if (lane == 0) wcnt[wave][e] = __popcll(bal);
    }
    __syncthreads();
    if (threadIdx.x < N_EXP) {
        int e = threadIdx.x; int a = 0;
        for (int wv = 0; wv < 4; ++wv) { wbase[wv][e] = a; a += wcnt[wv][e]; }
        bh[b * N_EXP + e] = a;
    }
    __syncthreads();
#pragma unroll
    for (int k = 0; k < TOP_K; ++k) {
        int e = topi[t * TOP_K + k];
        pose[t * TOP_K + k] = wbase[wave][e] + lrank[e];
    }
}

__global__ void scan16(const int* __restrict__ bh, int* __restrict__ bb,
                       int* __restrict__ off)
{
    __shared__ int tot[N_EXP];
    if (threadIdx.x < N_EXP) {
        int e = threadIdx.x; int a = 0;
        for (int b = 0; b < 16; ++b) { bb[b * N_EXP + e] = a; a += bh[b * N_EXP + e]; }
        tot[e] = a;
    }
    __syncthreads();
    if (threadIdx.x == 0) {
        int a = 0; off[0] = 0;
        for (int e = 0; e < N_EXP; ++e) { a += tot[e]; off[e + 1] = a; }
    }
}

__global__ __launch_bounds__(256)
void rank_final(const int* __restrict__ topi, const int* __restrict__ pose,
                const int* __restrict__ bb, const int* __restrict__ off,
                int* __restrict__ perm, int* __restrict__ slot_of)
{
    const int b = blockIdx.x;
    const int t = b * 256 + threadIdx.x;
#pragma unroll
    for (int k = 0; k < TOP_K; ++k) {
        int e = topi[t * TOP_K + k];
        int slot = off[e] + bb[b * N_EXP + e] + pose[t * TOP_K + k];
        perm[slot] = t;
        slot_of[t * TOP_K + k] = slot;
    }
}

template<bool YB>
__global__ __launch_bounds__(256)
void combine_k(const void* __restrict__ yv, const float* __restrict__ topw,
               const int* __restrict__ slot_of, float* __restrict__ h2,
               __bf16* __restrict__ h2b)
{
    int t = blockIdx.x;
    int64_t s[TOP_K]; float wgt[TOP_K];
#pragma unroll
    for (int k = 0; k < TOP_K; ++k) {
        s[k] = slot_of[t * TOP_K + k];
        wgt[k] = topw[t * TOP_K + k];
    }
    int64_t base4 = ((int64_t)t * D_MODEL) / 4 + threadIdx.x;
    float4 v = reinterpret_cast<const float4*>(h2)[base4];
#pragma unroll
    for (int k = 0; k < TOP_K; ++k) {
        float yy[4];
        if (YB) {
            bf16x4 yb = reinterpret_cast<const bf16x4*>((const __bf16*)yv)
                            [s[k] * (D_MODEL / 4) + threadIdx.x];
            yy[0] = (float)yb[0]; yy[1] = (float)yb[1];
            yy[2] = (float)yb[2]; yy[3] = (float)yb[3];
        } else {
            float4 yf = reinterpret_cast<const float4*>((const float*)yv)
                            [s[k] * (D_MODEL / 4) + threadIdx.x];
            yy[0] = yf.x; yy[1] = yf.y; yy[2] = yf.z; yy[3] = yf.w;
        }
        v.x = fmaf(wgt[k], yy[0], v.x);
        v.y = fmaf(wgt[k], yy[1], v.y);
        v.z = fmaf(wgt[k], yy[2], v.z);
        v.w = fmaf(wgt[k], yy[3], v.w);
    }
    if (h2b) {
        bf16x4 o;
        o[0] = (__bf16)v.x; o[1] = (__bf16)v.y;
        o[2] = (__bf16)v.z; o[3] = (__bf16)v.w;
        reinterpret_cast<bf16x4*>(h2b)[base4] = o;
    } else {
        reinterpret_cast<float4*>(h2)[base4] = v;
    }
}

// -------------------------------------------------------------------------
extern "C" void kernel_launch(void* const* d_in, const int* in_sizes, int n_in,
                              void* d_out, int out_size, void* d_ws, size_t ws_size,
                              hipStream_t stream)
{
    const float* x      = (const float*)d_in[0];
    const float* lin0_w = (const float*)d_in[1];
    const float* lin0_b = (const float*)d_in[2];
    const float* s1w1   = (const float*)d_in[3];
    const float* s1b1   = (const float*)d_in[4];
    const float* s1w2   = (const float*)d_in[5];
    const float* s1b2   = (const float*)d_in[6];
    const float* gate_w = (const float*)d_in[7];
    const float* ew1    = (const float*)d_in[8];
    const float* ew3    = (const float*)d_in[9];
    const float* ew2    = (const float*)d_in[10];
    const float* shw1   = (const float*)d_in[11];
    const float* shw3   = (const float*)d_in[12];
    const float* shw2   = (const float*)d_in[13];
    const float* lin1_w = (const float*)d_in[14];
    const float* lin1_b = (const float*)d_in[15];
    const float* s2w1   = (const float*)d_in[16];
    const float* s2b1   = (const float*)d_in[17];
    const float* s2w2   = (const float*)d_in[18];
    const float* s2b2   = (const float*)d_in[19];
    float* out = (float*)d_out;

    char* ws = (char*)d_ws;
    const size_t MB = 1024 * 1024;
    dim3 blk(256);
    const int64_t ES = (int64_t)D_MODEL * H_EXP;
    const bool full = ws_size >= (size_t)216 * MB;

    if (full) {
        // ---- round-10 proven arena ----
        float*  h0 = (float*)(ws + 0 * MB);
        float*  h1 = (float*)(ws + 16 * MB);
        float*  h2 = (float*)(ws + 32 * MB);
        __bf16* yexp_b = (__bf16*)(ws + 48 * MB);
        __bf16* gu_b   = (__bf16*)(ws + 80 * MB);
        __bf16* gsh_b  = gu_b;
        __bf16* h1b = (__bf16*)(ws + 112 * MB);
        __bf16* h2b = (__bf16*)(ws + 120 * MB);
        __bf16* h3b = (__bf16*)(ws + 128 * MB);
        __bf16* e1T = (__bf16*)(ws + 136 * MB);
        __bf16* e3T = (__bf16*)(ws + 152 * MB);
        __bf16* e2T = (__bf16*)(ws + 168 * MB);
        __bf16* s1T = (__bf16*)(ws + 184 * MB);
        __bf16* s3T = (__bf16*)(ws + 188 * MB);
        __bf16* s2T = (__bf16*)(ws + 192 * MB);
        __bf16* l1T = (__bf16*)(ws + 196 * MB);
        __bf16* q1T = (__bf16*)(ws + 198 * MB);
        __bf16* q2T = (__bf16*)(ws + 200 * MB);
        char* sm = ws + 202 * MB;
        int*   topi    = (int*)(sm);
        float* topw    = (float*)(sm + 64 * 1024);
        int*   pose    = (int*)(sm + 128 * 1024);
        int*   slot_of = (int*)(sm + 192 * 1024);
        int*   perm    = (int*)(sm + 256 * 1024);
        int*   bh      = (int*)(sm + 320 * 1024);
        int*   bb      = (int*)(sm + 321 * 1024);
        int*   off     = (int*)(sm + 322 * 1024);
        unsigned char* emask = (unsigned char*)(sm + 323 * 1024);

        // 0. weight transpose+convert (RNE)
        f2bT<<<dim3(32, 32, N_EXP), blk, 0, stream>>>(ew1, e1T, D_MODEL, H_EXP);
        f2bT<<<dim3(32, 32, N_EXP), blk, 0, stream>>>(ew3, e3T, D_MODEL, H_EXP);
        f2bT<<<dim3(32, 32, N_EXP), blk, 0, stream>>>(ew2, e2T, H_EXP, D_MODEL);
        f2bT<<<dim3(64, 32, 1), blk, 0, stream>>>(shw1, s1T, D_MODEL, SH_HID);
        f2bT<<<dim3(64, 32, 1), blk, 0, stream>>>(shw3, s3T, D_MODEL, SH_HID);
        f2bT<<<dim3(32, 64, 1), blk, 0, stream>>>(shw2, s2T, SH_HID, D_MODEL);
        f2bT<<<dim3(32, 32, 1), blk, 0, stream>>>(lin1_w, l1T, D_MODEL, D_MODEL);
        f2bT<<<dim3(32, 32, 1), blk, 0, stream>>>(s2w1, q1T, D_MODEL, D_MODEL);
        f2bT<<<dim3(32, 32, 1), blk, 0, stream>>>(s2w2, q2T, D_MODEL, D_MODEL);

        // 1. lin0 (split3, router prefix)
        gemm_sp<3, false, false, false><<<dim3(8, 32, 1), blk, 0, stream>>>(
            x, D_MODEL, lin0_w, nullptr, 0, D_MODEL, lin0_b, nullptr,
            h0, nullptr, D_MODEL, T_TOKENS, D_MODEL, nullptr, nullptr);

        // 2. swi1 fused-GLU (split3) -> h1 fp32 + h1b bf16
        gemm_sp<3, false, false, true><<<dim3(16, 32, 1), blk, 0, stream>>>(
            h0, D_MODEL, s1w1, s1w2, 0, D_MODEL, s1b1, s1b2,
            h1, h1b, D_MODEL, T_TOKENS, D_MODEL, nullptr, nullptr);

        // 3. router
        router_logits<<<T_TOKENS / 4, blk, 0, stream>>>(h1, gate_w, topi, topw, emask);
        rank_local<<<16, blk, 0, stream>>>(emask, topi, pose, bh);
        scan16<<<1, 64, 0, stream>>>(bh, bb, off);
        rank_final<<<16, blk, 0, stream>>>(topi, pose, bb, off, perm, slot_of);

        // 4. expA GLU -> gu_b   (BK=64, split half-tile layout)
        gemm_b64<true, true, true, true><<<dim3(16, 128, N_EXP), blk, 0, stream>>>(
            h1b, D_MODEL, e1T, e3T, ES, D_MODEL, nullptr, nullptr,
            nullptr, gu_b, H_EXP, 0, D_MODEL, off, perm);
        // 5. expB -> yexp_b
        gemm_b64<true, false, false, true><<<dim3(8, 128, N_EXP), blk, 0, stream>>>(
            gu_b, H_EXP, e2T, nullptr, ES, H_EXP, nullptr, nullptr,
            nullptr, yexp_b, D_MODEL, 0, H_EXP, off, nullptr);
        // 6. shA GLU -> gsh_b (aliases gu_b, dead)
        gemm_b64<false, false, true, true><<<dim3(32, 32, 1), blk, 0, stream>>>(
            h1b, D_MODEL, s1T, s3T, 0, D_MODEL, nullptr, nullptr,
            nullptr, gsh_b, SH_HID, T_TOKENS, D_MODEL, nullptr, nullptr);
        // 7. shB -> h2 fp32
        gemm_b64<false, false, false, false><<<dim3(8, 32, 1), blk, 0, stream>>>(
            gsh_b, SH_HID, s2T, nullptr, 0, SH_HID, nullptr, nullptr,
            h2, nullptr, D_MODEL, T_TOKENS, SH_HID, nullptr, nullptr);

        // 8. combine -> h2b
        combine_k<true><<<T_TOKENS, blk, 0, stream>>>(yexp_b, topw, slot_of, h2, h2b);

        // 9. lin1 (bf16, +bias) -> h3b
        gemm_b64<false, false, false, true><<<dim3(8, 32, 1), blk, 0, stream>>>(
            h2b, D_MODEL, l1T, nullptr, 0, D_MODEL, lin1_b, nullptr,
            nullptr, h3b, D_MODEL, T_TOKENS, D_MODEL, nullptr, nullptr);

        // 10. swi2 fused-GLU (bf16, +biases) -> out fp32
        gemm_b64<false, false, true, false><<<dim3(16, 32, 1), blk, 0, stream>>>(
            h3b, D_MODEL, q1T, q2T, 0, D_MODEL, s2b1, s2b2,
            out, nullptr, D_MODEL, T_TOKENS, D_MODEL, nullptr, nullptr);
    } else {
        // ---- fallback (round-10 proven, <216 MB) ----
        float* h0 = (float*)(ws + 0 * MB);
        float* h1 = (float*)(ws + 16 * MB);
        float* h2 = (float*)(ws + 32 * MB);
        float* yexp  = (float*)(ws + 48 * MB);
        __bf16* gu_b = (__bf16*)(ws + 112 * MB);
        __bf16* gsh_b = gu_b;
        __bf16* h1b  = (__bf16*)(ws + 144 * MB);
        char* sm = ws + 152 * MB;
        int*   topi    = (int*)(sm);
        float* topw    = (float*)(sm + 64 * 1024);
        int*   pose    = (int*)(sm + 128 * 1024);
        int*   slot_of = (int*)(sm + 192 * 1024);
        int*   perm    = (int*)(sm + 256 * 1024);
        int*   bh      = (int*)(sm + 320 * 1024);
        int*   bb      = (int*)(sm + 321 * 1024);
        int*   off     = (int*)(sm + 322 * 1024);
        unsigned char* emask = (unsigned char*)(sm + 323 * 1024);

        gemm_sp<3, false, false, false><<<dim3(8, 32, 1), blk, 0, stream>>>(
            x, D_MODEL, lin0_w, nullptr, 0, D_MODEL, lin0_b, nullptr,
            h0, nullptr, D_MODEL, T_TOKENS, D_MODEL, nullptr, nullptr);
        gemm_sp<3, false, false, true><<<dim3(16, 32, 1), blk, 0, stream>>>(
            h0, D_MODEL, s1w1, s1w2, 0, D_MODEL, s1b1, s1b2,
            h1, h1b, D_MODEL, T_TOKENS, D_MODEL, nullptr, nullptr);

        router_logits<<<T_TOKENS / 4, blk, 0, stream>>>(h1, gate_w, topi, topw, emask);
        rank_local<<<16, blk, 0, stream>>>(emask, topi, pose, bh);
        scan16<<<1, 64, 0, stream>>>(bh, bb, off);
        rank_final<<<16, blk, 0, stream>>>(topi, pose, bb, off, perm, slot_of);

        gemm_bb<false, true, true, true, true><<<dim3(16, 128, N_EXP), blk, 0, stream>>>(
            h1b, D_MODEL, ew1, ew3, ES, H_EXP, nullptr, nullptr,
            nullptr, gu_b, H_EXP, 0, D_MODEL, off, perm);
        gemm_bb<false, true, false, false, false><<<dim3(8, 128, N_EXP), blk, 0, stream>>>(
            gu_b, H_EXP, ew2, nullptr, (int64_t)H_EXP * D_MODEL, D_MODEL, nullptr, nullptr,
            yexp, nullptr, D_MODEL, 0, H_EXP, off, nullptr);
        gemm_bb<false, false, false, true, true><<<dim3(32, 32, 1), blk, 0, stream>>>(
            h1b, D_MODEL, shw1, shw3, 0, SH_HID, nullptr, nullptr,
            nullptr, gsh_b, SH_HID, T_TOKENS, D_MODEL, nullptr, nullptr);
        gemm_bb<false, false, false, false, false><<<dim3(8, 32, 1), blk, 0, stream>>>(
            gsh_b, SH_HID, shw2, nullptr, 0, D_MODEL, nullptr, nullptr,
            h2, nullptr, D_MODEL, T_TOKENS, SH_HID, nullptr, nullptr);

        combine_k<false><<<T_TOKENS, blk, 0, stream>>>(yexp, topw, slot_of, h2, nullptr);

        gemm_sp<2, false, false, false><<<dim3(8, 32, 1), blk, 0, stream>>>(
            h2, D_MODEL, lin1_w, nullptr, 0, D_MODEL, lin1_b, nullptr,
            h0, nullptr, D_MODEL, T_TOKENS, D_MODEL, nullptr, nullptr);
        gemm_sp<2, false, false, true><<<dim3(16, 32, 1), blk, 0, stream>>>(
            h0, D_MODEL, s2w1, s2w2, 0, D_MODEL, s2b1, s2b2,
            out, nullptr, D_MODEL, T_TOKENS, D_MODEL, nullptr, nullptr);
    }
}

// Round 17
// 566.731 us; speedup vs baseline: 1.0397x; 1.0397x over previous
//
#include <hip/hip_runtime.h>
#include <cstdint>
#include <cstddef>

#define T_TOKENS 4096
#define D_MODEL  1024
#define N_EXP    8
#define TOP_K    4
#define H_EXP    1024
#define SH_HID   2048
#define TK       (T_TOKENS*TOP_K)

typedef __bf16 bf16x8 __attribute__((ext_vector_type(8)));
typedef __bf16 bf16x4 __attribute__((ext_vector_type(4)));
typedef float  f32x4  __attribute__((ext_vector_type(4)));

__device__ __forceinline__ float silu_f(float x) {
    return x / (1.0f + expf(-x));
}

// =========================================================================
// gemm_sp (proven): fp32 A, fp32 W, in-loop split conversion.
// NT=3: 6 MFMA terms, fp32-grade — router-feeding prefix (+ fallback path).
// =========================================================================
template<int NT, bool SEG, bool GATHER, bool GLU>
__global__ __launch_bounds__(256)
void gemm_sp(const float* __restrict__ A, int lda,
             const float* __restrict__ W1, const float* __restrict__ W3,
             int64_t w_estride, int ldw,
             const float* __restrict__ bias1, const float* __restrict__ bias2,
             float* __restrict__ C, __bf16* __restrict__ Cb1, int ldc,
             int M, int Kd,
             const int* __restrict__ seg_off,
             const int* __restrict__ gather)
{
    constexpr int BM = 128, BN = 128, BK = 32;
    __shared__ __bf16 Asl[NT][BM * BK];
    __shared__ __bf16 Bsl[NT][BN * BK];

    int m0, m1, e = 0;
    if (SEG) {
        e = blockIdx.z;
        int s0 = seg_off[e], s1 = seg_off[e + 1];
        m0 = s0 + blockIdx.y * BM;
        if (m0 >= s1) return;
        m1 = (m0 + BM < s1) ? (m0 + BM) : s1;
    } else {
        m0 = blockIdx.y * BM;
        m1 = (m0 + BM < M) ? (m0 + BM) : M;
    }
    const int n0 = blockIdx.x * BN;

    const int tid  = threadIdx.x;
    const int lane = tid & 63;
    const int w    = tid >> 6;
    const int wm   = w >> 1, wn = w & 1;
    const int fr   = lane & 15, fq = lane >> 4;

    const float* aP[4]; int aR[4], aQ[4];
#pragma unroll
    for (int i = 0; i < 4; ++i) {
        int Li = tid + 256 * i;
        int r = Li >> 3, q = Li & 7;
        aR[i] = r; aQ[i] = q;
        int grow = m0 + r;
        if (grow > m1 - 1) grow = m1 - 1;
        if (GATHER) grow = gather[grow];
        aP[i] = A + (int64_t)grow * lda + q * 4;
    }

    const int bn  = tid & 127;
    const int bkh = tid >> 7;
    const float* Wsrc; int wcol;
    if (GLU) {
        int cl = n0 + bn;
        int B  = cl >> 4;
        Wsrc = (B & 1) ? W3 : W1;
        wcol = ((B >> 1) << 4) | (cl & 15);
    } else {
        Wsrc = W1; wcol = n0 + bn;
    }
    const float* Wb = Wsrc + (int64_t)e * w_estride + (int64_t)(bkh * 16) * ldw + wcol;

    f32x4 zero4 = {0.f, 0.f, 0.f, 0.f};
    f32x4 acc[4][4];
#pragma unroll
    for (int i = 0; i < 4; ++i)
#pragma unroll
        for (int j = 0; j < 4; ++j) acc[i][j] = zero4;

    float4 av[4];
    float  wv[16];

#define GLOADS(K0)                                                         \
    do {                                                                   \
        _Pragma("unroll")                                                  \
        for (int i = 0; i < 4; ++i)                                        \
            av[i] = *reinterpret_cast<const float4*>(aP[i] + (K0));        \
        _Pragma("unroll")                                                  \
        for (int j = 0; j < 16; ++j)                                       \
            wv[j] = Wb[(int64_t)((K0) + j) * ldw];                         \
    } while (0)

    const int nk = Kd / BK;
    GLOADS(0);

    for (int ks = 0; ks < nk; ++ks) {
        bf16x4 pa[NT][4];
        bf16x4 pw[NT][4];
#pragma unroll
        for (int i = 0; i < 4; ++i) {
            float vv[4] = {av[i].x, av[i].y, av[i].z, av[i].w};
#pragma unroll
            for (int t = 0; t < 4; ++t) {
                float v = vv[t];
                __bf16 h = (__bf16)v;
                pa[0][i][t] = h;
                if (NT >= 2) {
                    float r = v - (float)h;
                    if (NT == 2) {
                        pa[1][i][t] = (__bf16)r;
                    } else {
                        __bf16 m = (__bf16)r;
                        pa[1][i][t] = m;
                        pa[2][i][t] = (__bf16)(r - (float)m);
                    }
                }
            }
        }
#pragma unroll
        for (int qd = 0; qd < 4; ++qd) {
#pragma unroll
            for (int t = 0; t < 4; ++t) {
                float v = wv[qd * 4 + t];
                __bf16 h = (__bf16)v;
                pw[0][qd][t] = h;
                if (NT >= 2) {
                    float r = v - (float)h;
                    if (NT == 2) {
                        pw[1][qd][t] = (__bf16)r;
                    } else {
                        __bf16 m = (__bf16)r;
                        pw[1][qd][t] = m;
                        pw[2][qd][t] = (__bf16)(r - (float)m);
                    }
                }
            }
        }

        __syncthreads();
#pragma unroll
        for (int i = 0; i < 4; ++i) {
            int r = aR[i], q = aQ[i];
            int c = (q >> 1) ^ ((r >> 1) & 3);
            int idx = r * BK + c * 8 + (q & 1) * 4;
#pragma unroll
            for (int p = 0; p < NT; ++p)
                *reinterpret_cast<bf16x4*>(&Asl[p][idx]) = pa[p][i];
        }
#pragma unroll
        for (int qd = 0; qd < 4; ++qd) {
            int q32 = bkh * 4 + qd;
            int c = (q32 >> 1) ^ ((bn >> 1) & 3);
            int idx = bn * BK + c * 8 + (q32 & 1) * 4;
#pragma unroll
            for (int p = 0; p < NT; ++p)
                *reinterpret_cast<bf16x4*>(&Bsl[p][idx]) = pw[p][qd];
        }

        if (ks + 1 < nk) GLOADS((ks + 1) * BK);
        __syncthreads();

        bf16x8 bfr[NT][4];
#pragma unroll
        for (int p = 0; p < NT; ++p)
#pragma unroll
            for (int j = 0; j < 4; ++j) {
                int rown = wn * 64 + j * 16 + fr;
                int c = fq ^ ((rown >> 1) & 3);
                bfr[p][j] = *reinterpret_cast<const bf16x8*>(&Bsl[p][rown * BK + c * 8]);
            }
#pragma unroll
        for (int im = 0; im < 4; ++im) {
            bf16x8 af[NT];
            int rowm = wm * 64 + im * 16 + fr;
            int c = fq ^ ((rowm >> 1) & 3);
#pragma unroll
            for (int p = 0; p < NT; ++p)
                af[p] = *reinterpret_cast<const bf16x8*>(&Asl[p][rowm * BK + c * 8]);
#pragma unroll
            for (int jn = 0; jn < 4; ++jn) {
                f32x4 a = acc[im][jn];
                a = __builtin_amdgcn_mfma_f32_16x16x32_bf16(af[0], bfr[0][jn], a, 0, 0, 0);
                if (NT >= 2) {
                    a = __builtin_amdgcn_mfma_f32_16x16x32_bf16(af[0], bfr[1][jn], a, 0, 0, 0);
                    a = __builtin_amdgcn_mfma_f32_16x16x32_bf16(af[1], bfr[0][jn], a, 0, 0, 0);
                }
                if (NT == 3) {
                    a = __builtin_amdgcn_mfma_f32_16x16x32_bf16(af[1], bfr[1][jn], a, 0, 0, 0);
                    a = __builtin_amdgcn_mfma_f32_16x16x32_bf16(af[0], bfr[2][jn], a, 0, 0, 0);
                    a = __builtin_amdgcn_mfma_f32_16x16x32_bf16(af[2], bfr[0][jn], a, 0, 0, 0);
                }
                acc[im][jn] = a;
            }
        }
    }
#undef GLOADS

    if (GLU) {
#pragma unroll
        for (int jn = 0; jn < 4; jn += 2) {
            int gcol = (n0 >> 1) + wn * 32 + (jn >> 1) * 16 + fr;
            float bv1 = bias1 ? bias1[gcol] : 0.f;
            float bv2 = bias2 ? bias2[gcol] : 0.f;
#pragma unroll
            for (int im = 0; im < 4; ++im) {
                f32x4 v1 = acc[im][jn];
                f32x4 v2 = acc[im][jn + 1];
#pragma unroll
                for (int r = 0; r < 4; ++r) {
                    int grow = m0 + wm * 64 + im * 16 + fq * 4 + r;
                    if (grow < m1) {
                        float val = silu_f(v1[r] + bv1) * (v2[r] + bv2);
                        int64_t o = (int64_t)grow * ldc + gcol;
                        C[o] = val;
                        if (Cb1) Cb1[o] = (__bf16)val;
                    }
                }
            }
        }
    } else {
#pragma unroll
        for (int jn = 0; jn < 4; ++jn) {
            int col = n0 + wn * 64 + jn * 16 + fr;
            float bv = bias1 ? bias1[col] : 0.f;
#pragma unroll
            for (int im = 0; im < 4; ++im) {
                f32x4 v = acc[im][jn];
#pragma unroll
                for (int r = 0; r < 4; ++r) {
                    int grow = m0 + wm * 64 + im * 16 + fq * 4 + r;
                    if (grow < m1)
                        C[(int64_t)grow * ldc + col] = v[r] + bv;
                }
            }
        }
    }
}

// =========================================================================
// gemm_b64 (round-14 proven BEST): 128x128, 4 waves, 64x64 wave tile,
// BK=64 — halves barrier count per K vs BK=32. Per-accumulator K order
// stays sequential (two MFMAs per frag pair: k, k+32) -> bit-identical.
// W pre-transposed bf16 [N][K] (ldw = Kd). 2-bit chunk swizzle per
// 32-wide half (residual write-side bank aliasing measured as hidden
// under global-load latency; both alternative layouts regressed).
// =========================================================================
template<bool SEG, bool GATHER, bool GLU, bool EMITB>
__global__ __launch_bounds__(256)
void gemm_b64(const __bf16* __restrict__ A, int lda,
              const __bf16* __restrict__ W1, const __bf16* __restrict__ W3,
              int64_t w_estride, int ldw,
              const float* __restrict__ bias1, const float* __restrict__ bias2,
              float* __restrict__ C, __bf16* __restrict__ Cb, int ldc,
              int M, int Kd,
              const int* __restrict__ seg_off,
              const int* __restrict__ gather)
{
    constexpr int BK = 64;
    __shared__ __bf16 Asl[128 * BK];   // 16 KB
    __shared__ __bf16 Bsl[128 * BK];   // 16 KB

    int m0, m1, e = 0;
    if (SEG) {
        e = blockIdx.z;
        int s0 = seg_off[e], s1 = seg_off[e + 1];
        m0 = s0 + blockIdx.y * 128;
        if (m0 >= s1) return;
        m1 = (m0 + 128 < s1) ? (m0 + 128) : s1;
    } else {
        m0 = blockIdx.y * 128;
        m1 = (m0 + 128 < M) ? (m0 + 128) : M;
    }
    const int n0 = blockIdx.x * 128;

    const int tid  = threadIdx.x;
    const int lane = tid & 63;
    const int w    = tid >> 6;
    const int wm   = w >> 1, wn = w & 1;
    const int fr   = lane & 15, fq = lane >> 4;

    // ---- A staging: 4 x bf16x8 (128 rows x 8 chunks / 256 threads)
    int aWr[4]; const __bf16* Ab[4];
#pragma unroll
    for (int i = 0; i < 4; ++i) {
        int L = tid + 256 * i;
        int r = L >> 3, ch = L & 7;
        int half = ch >> 2, c32 = ch & 3;
        aWr[i] = r * BK + half * 32 + (c32 ^ ((r >> 1) & 3)) * 8;
        int grow = m0 + r;
        if (grow > m1 - 1) grow = m1 - 1;
        if (GATHER) grow = gather[grow];
        Ab[i] = A + (int64_t)grow * lda + ch * 8;
    }

    // ---- W staging: 4 x bf16x8 (128 W^T rows x 8 chunks / 256 threads)
    int wR[4]; const __bf16* Wt[4];
#pragma unroll
    for (int i = 0; i < 4; ++i) {
        int L = tid + 256 * i;
        int nl = L >> 3, ch = L & 7;
        int half = ch >> 2, c32 = ch & 3;
        wR[i] = nl * BK + half * 32 + (c32 ^ ((nl >> 1) & 3)) * 8;
        int cl = n0 + nl;
        const __bf16* base; int srcrow;
        if (GLU) {
            int B = cl >> 4;
            base = (B & 1) ? W3 : W1;
            srcrow = ((B >> 1) << 4) | (cl & 15);
        } else {
            base = W1; srcrow = cl;
        }
        Wt[i] = base + (int64_t)e * w_estride + (int64_t)srcrow * ldw + ch * 8;
    }

    f32x4 zero4 = {0.f, 0.f, 0.f, 0.f};
    f32x4 acc[4][4];
#pragma unroll
    for (int i = 0; i < 4; ++i)
#pragma unroll
        for (int j = 0; j < 4; ++j) acc[i][j] = zero4;

    bf16x8 areg[4];
    bf16x8 wreg[4];

#define GLOADS(K0)                                                          \
    do {                                                                    \
        _Pragma("unroll")                                                   \
        for (int i = 0; i < 4; ++i) {                                       \
            areg[i] = *reinterpret_cast<const bf16x8*>(Ab[i] + (K0));       \
            wreg[i] = *reinterpret_cast<const bf16x8*>(Wt[i] + (K0));       \
        }                                                                   \
    } while (0)

    const int nk = Kd / BK;
    GLOADS(0);

    for (int ks = 0; ks < nk; ++ks) {
        __syncthreads();
#pragma unroll
        for (int i = 0; i < 4; ++i) {
            *reinterpret_cast<bf16x8*>(&Asl[aWr[i]]) = areg[i];
            *reinterpret_cast<bf16x8*>(&Bsl[wR[i]]) = wreg[i];
        }
        if (ks + 1 < nk) GLOADS((ks + 1) * BK);
        __syncthreads();

        bf16x8 bfr[2][4];
#pragma unroll
        for (int h = 0; h < 2; ++h)
#pragma unroll
            for (int j = 0; j < 4; ++j) {
                int rown = wn * 64 + j * 16 + fr;
                int c = fq ^ ((rown >> 1) & 3);
                bfr[h][j] = *reinterpret_cast<const bf16x8*>(&Bsl[rown * BK + h * 32 + c * 8]);
            }
#pragma unroll
        for (int im = 0; im < 4; ++im) {
            int rowm = wm * 64 + im * 16 + fr;
            int c = fq ^ ((rowm >> 1) & 3);
            bf16x8 af0 = *reinterpret_cast<const bf16x8*>(&Asl[rowm * BK + c * 8]);
            bf16x8 af1 = *reinterpret_cast<const bf16x8*>(&Asl[rowm * BK + 32 + c * 8]);
#pragma unroll
            for (int jn = 0; jn < 4; ++jn) {
                f32x4 a = acc[im][jn];
                a = __builtin_amdgcn_mfma_f32_16x16x32_bf16(af0, bfr[0][jn], a, 0, 0, 0);
                a = __builtin_amdgcn_mfma_f32_16x16x32_bf16(af1, bfr[1][jn], a, 0, 0, 0);
                acc[im][jn] = a;
            }
        }
    }
#undef GLOADS

    if (GLU) {
#pragma unroll
        for (int jn = 0; jn < 4; jn += 2) {
            int gcol = (n0 >> 1) + wn * 32 + (jn >> 1) * 16 + fr;
            float bv1 = bias1 ? bias1[gcol] : 0.f;
            float bv2 = bias2 ? bias2[gcol] : 0.f;
#pragma unroll
            for (int im = 0; im < 4; ++im) {
                f32x4 v1 = acc[im][jn];
                f32x4 v2 = acc[im][jn + 1];
#pragma unroll
                for (int r = 0; r < 4; ++r) {
                    int grow = m0 + wm * 64 + im * 16 + fq * 4 + r;
                    if (grow < m1) {
                        float val = silu_f(v1[r] + bv1) * (v2[r] + bv2);
                        int64_t o = (int64_t)grow * ldc + gcol;
                        if (EMITB) Cb[o] = (__bf16)val;
                        else       C[o]  = val;
                    }
                }
            }
        }
    } else {
#pragma unroll
        for (int jn = 0; jn < 4; ++jn) {
            int col = n0 + wn * 64 + jn * 16 + fr;
            float bv = bias1 ? bias1[col] : 0.f;
#pragma unroll
            for (int im = 0; im < 4; ++im) {
                f32x4 v = acc[im][jn];
#pragma unroll
                for (int r = 0; r < 4; ++r) {
                    int grow = m0 + wm * 64 + im * 16 + fq * 4 + r;
                    if (grow < m1) {
                        int64_t o = (int64_t)grow * ldc + col;
                        if (EMITB) Cb[o] = (__bf16)(v[r] + bv);
                        else       C[o]  = v[r] + bv;
                    }
                }
            }
        }
    }
}

// =========================================================================
// gemm_bb (round-10 proven, WBF=false strided path): fallback only.
// =========================================================================
template<bool WBF, bool SEG, bool GATHER, bool GLU, bool EMITB>
__global__ __launch_bounds__(256)
void gemm_bb(const __bf16* __restrict__ A, int lda,
             const void* __restrict__ W1v, const void* __restrict__ W3v,
             int64_t w_estride, int ldw,
             const float* __restrict__ bias1, const float* __restrict__ bias2,
             float* __restrict__ C, __bf16* __restrict__ Cb, int ldc,
             int M, int Kd,
             const int* __restrict__ seg_off,
             const int* __restrict__ gather)
{
    constexpr int BK = 32;
    __shared__ __bf16 Asl[128 * BK];
    __shared__ __bf16 Bsl[128 * BK];

    int m0, m1, e = 0;
    if (SEG) {
        e = blockIdx.z;
        int s0 = seg_off[e], s1 = seg_off[e + 1];
        m0 = s0 + blockIdx.y * 128;
        if (m0 >= s1) return;
        m1 = (m0 + 128 < s1) ? (m0 + 128) : s1;
    } else {
        m0 = blockIdx.y * 128;
        m1 = (m0 + 128 < M) ? (m0 + 128) : M;
    }
    const int n0 = blockIdx.x * 128;

    const int tid  = threadIdx.x;
    const int lane = tid & 63;
    const int w    = tid >> 6;
    const int wm   = w >> 1, wn = w & 1;
    const int fr   = lane & 15, fq = lane >> 4;

    int aWr[2]; const __bf16* Ab[2];
#pragma unroll
    for (int i = 0; i < 2; ++i) {
        int L = tid + 256 * i;
        int r = L >> 2, ch = L & 3;
        aWr[i] = r * BK + (ch ^ ((r >> 1) & 3)) * 8;
        int grow = m0 + r;
        if (grow > m1 - 1) grow = m1 - 1;
        if (GATHER) grow = gather[grow];
        Ab[i] = A + (int64_t)grow * lda + ch * 8;
    }

    int wR[2]; const __bf16* Wt[2];
    const float* Wbf = nullptr;
    int wWrS[2];
    if (WBF) {
#pragma unroll
        for (int i = 0; i < 2; ++i) {
            int L = tid + 256 * i;
            int nl = L >> 2, ch = L & 3;
            wR[i] = nl * BK + (ch ^ ((nl >> 1) & 3)) * 8;
            int cl = n0 + nl;
            const __bf16* base;
            int srcrow;
            if (GLU) {
                int B = cl >> 4;
                base = (const __bf16*)((B & 1) ? W3v : W1v);
                srcrow = ((B >> 1) << 4) | (cl & 15);
            } else {
                base = (const __bf16*)W1v;
                srcrow = cl;
            }
            Wt[i] = base + (int64_t)e * w_estride + (int64_t)srcrow * ldw + ch * 8;
        }
    } else {
        const int bn  = tid & 127;
        const int bkh = tid >> 7;
        int wcol; const void* Wsel;
        if (GLU) {
            int cl = n0 + bn;
            int B  = cl >> 4;
            Wsel = (B & 1) ? W3v : W1v;
            wcol = ((B >> 1) << 4) | (cl & 15);
        } else {
            Wsel = W1v; wcol = n0 + bn;
        }
        Wbf = (const float*)Wsel + (int64_t)e * w_estride + (int64_t)(bkh * 16) * ldw + wcol;
#pragma unroll
        for (int c = 0; c < 2; ++c)
            wWrS[c] = bn * BK + ((bkh * 2 + c) ^ ((bn >> 1) & 3)) * 8;
    }

    f32x4 zero4 = {0.f, 0.f, 0.f, 0.f};
    f32x4 acc[4][4];
#pragma unroll
    for (int i = 0; i < 4; ++i)
#pragma unroll
        for (int j = 0; j < 4; ++j) acc[i][j] = zero4;

    bf16x8 areg[2];
    bf16x8 wreg[2];

#define GLOADS(K0)                                                          \
    do {                                                                    \
        areg[0] = *reinterpret_cast<const bf16x8*>(Ab[0] + (K0));           \
        areg[1] = *reinterpret_cast<const bf16x8*>(Ab[1] + (K0));           \
        if (WBF) {                                                          \
            wreg[0] = *reinterpret_cast<const bf16x8*>(Wt[0] + (K0));       \
            wreg[1] = *reinterpret_cast<const bf16x8*>(Wt[1] + (K0));       \
        } else {                                                            \
            _Pragma("unroll")                                               \
            for (int j = 0; j < 16; ++j)                                    \
                wreg[j >> 3][j & 7] = (__bf16)Wbf[(int64_t)((K0) + j) * ldw]; \
        }                                                                   \
    } while (0)

    const int nk = Kd / BK;
    GLOADS(0);

    for (int ks = 0; ks < nk; ++ks) {
        __syncthreads();
        *reinterpret_cast<bf16x8*>(&Asl[aWr[0]]) = areg[0];
        *reinterpret_cast<bf16x8*>(&Asl[aWr[1]]) = areg[1];
        if (WBF) {
            *reinterpret_cast<bf16x8*>(&Bsl[wR[0]]) = wreg[0];
            *reinterpret_cast<bf16x8*>(&Bsl[wR[1]]) = wreg[1];
        } else {
            *reinterpret_cast<bf16x8*>(&Bsl[wWrS[0]]) = wreg[0];
            *reinterpret_cast<bf16x8*>(&Bsl[wWrS[1]]) = wreg[1];
        }
        if (ks + 1 < nk) GLOADS((ks + 1) * BK);
        __syncthreads();

        bf16x8 bfr[4];
#pragma unroll
        for (int j = 0; j < 4; ++j) {
            int rown = wn * 64 + j * 16 + fr;
            int c = fq ^ ((rown >> 1) & 3);
            bfr[j] = *reinterpret_cast<const bf16x8*>(&Bsl[rown * BK + c * 8]);
        }
#pragma unroll
        for (int im = 0; im < 4; ++im) {
            int rowm = wm * 64 + im * 16 + fr;
            int c = fq ^ ((rowm >> 1) & 3);
            bf16x8 af = *reinterpret_cast<const bf16x8*>(&Asl[rowm * BK + c * 8]);
#pragma unroll
            for (int jn = 0; jn < 4; ++jn)
                acc[im][jn] = __builtin_amdgcn_mfma_f32_16x16x32_bf16(af, bfr[jn], acc[im][jn], 0, 0, 0);
        }
    }
#undef GLOADS

    if (GLU) {
#pragma unroll
        for (int jn = 0; jn < 4; jn += 2) {
            int gcol = (n0 >> 1) + wn * 32 + (jn >> 1) * 16 + fr;
            float bv1 = bias1 ? bias1[gcol] : 0.f;
            float bv2 = bias2 ? bias2[gcol] : 0.f;
#pragma unroll
            for (int im = 0; im < 4; ++im) {
                f32x4 v1 = acc[im][jn];
                f32x4 v2 = acc[im][jn + 1];
#pragma unroll
                for (int r = 0; r < 4; ++r) {
                    int grow = m0 + wm * 64 + im * 16 + fq * 4 + r;
                    if (grow < m1) {
                        float val = silu_f(v1[r] + bv1) * (v2[r] + bv2);
                        int64_t o = (int64_t)grow * ldc + gcol;
                        if (EMITB) Cb[o] = (__bf16)val;
                        else       C[o]  = val;
                    }
                }
            }
        }
    } else {
#pragma unroll
        for (int jn = 0; jn < 4; ++jn) {
            int col = n0 + wn * 64 + jn * 16 + fr;
            float bv = bias1 ? bias1[col] : 0.f;
#pragma unroll
            for (int im = 0; im < 4; ++im) {
                f32x4 v = acc[im][jn];
#pragma unroll
                for (int r = 0; r < 4; ++r) {
                    int grow = m0 + wm * 64 + im * 16 + fq * 4 + r;
                    if (grow < m1) {
                        int64_t o = (int64_t)grow * ldc + col;
                        if (EMITB) Cb[o] = (__bf16)(v[r] + bv);
                        else       C[o]  = v[r] + bv;
                    }
                }
            }
        }
    }
}

// -------------------------------------------------------------------------
// Transpose + fp32->bf16 (RNE): src fp32 [R][C] -> dst bf16 [C][R].
// -------------------------------------------------------------------------
__global__ __launch_bounds__(256)
void f2bT(const float* __restrict__ src, __bf16* __restrict__ dst, int R, int C)
{
    __shared__ float t[32][33];
    const int64_t eoff = (int64_t)blockIdx.z * R * C;
    src += eoff; dst += eoff;
    const int c0 = blockIdx.x * 32, r0 = blockIdx.y * 32;
    const int tx = threadIdx.x & 31, ty = threadIdx.x >> 5;
#pragma unroll
    for (int i = 0; i < 4; ++i) {
        int r = r0 + ty + i * 8;
        t[ty + i * 8][tx] = src[(int64_t)r * C + c0 + tx];
    }
    __syncthreads();
#pragma unroll
    for (int i = 0; i < 4; ++i) {
        int c = c0 + ty + i * 8;
        dst[(int64_t)c * R + r0 + tx] = (__bf16)t[tx][ty + i * 8];
    }
}

// -------------------------------------------------------------------------
// Router (atomic-free ballot rank/scan, proven)
// -------------------------------------------------------------------------
__global__ __launch_bounds__(256)
void router_logits(const float* __restrict__ h1, const float* __restrict__ gw,
                   int* __restrict__ topi, float* __restrict__ topw,
                   unsigned char* __restrict__ emask)
{
    const int wave = threadIdx.x >> 6, lane = threadIdx.x & 63;
    const int t = blockIdx.x * 4 + wave;
    const float* x = h1 + (int64_t)t * D_MODEL;
    float part[N_EXP];
#pragma unroll
    for (int e = 0; e < N_EXP; ++e) part[e] = 0.f;
#pragma unroll 4
    for (int i = 0; i < D_MODEL / 64; ++i) {
        int d = lane + 64 * i;
        float xv = x[d];
#pragma unroll
        for (int e = 0; e < N_EXP; ++e)
            part[e] = fmaf(xv, gw[e * D_MODEL + d], part[e]);
    }
#pragma unroll
    for (int m = 32; m > 0; m >>= 1)
#pragma unroll
        for (int e = 0; e < N_EXP; ++e)
            part[e] += __shfl_xor(part[e], m, 64);

    if (lane == 0) {
        float p[N_EXP];
        float mx = -1e30f;
#pragma unroll
        for (int e = 0; e < N_EXP; ++e) mx = part[e] > mx ? part[e] : mx;
        float z = 0.f;
#pragma unroll
        for (int e = 0; e < N_EXP; ++e) { p[e] = expf(part[e] - mx); z += p[e]; }
#pragma unroll
        for (int e = 0; e < N_EXP; ++e) p[e] /= z;
        bool used[N_EXP];
#pragma unroll
        for (int e = 0; e < N_EXP; ++e) used[e] = false;
        int sel[TOP_K]; float sv[TOP_K]; float wsum = 0.f;
        unsigned m8 = 0;
        for (int k = 0; k < TOP_K; ++k) {
            int best = 0; float bvv = -1.f;
            for (int e = 0; e < N_EXP; ++e)
                if (!used[e] && p[e] > bvv) { bvv = p[e]; best = e; }
            used[best] = true; sel[k] = best; sv[k] = bvv; wsum += bvv;
            m8 |= 1u << best;
        }
        for (int k = 0; k < TOP_K; ++k) {
            int idx = t * TOP_K + k;
            topi[idx] = sel[k];
            topw[idx] = sv[k] / wsum;
        }
        emask[t] = (unsigned char)m8;
    }
}

__global__ __launch_bounds__(256)
void rank_local(const unsigned char* __restrict__ emask,
                const int* __restrict__ topi,
                int* __restrict__ pose, int* __restrict__ bh)
{
    const int b = blockIdx.x;
    const int t = b * 256 + threadIdx.x;
    const int wave = threadIdx.x >> 6, lane = threadIdx.x & 63;
    const unsigned m8 = emask[t];

    __shared__ int wcnt[4][N_EXP];
    __shared__ int wbase[4][N_EXP];
    int lrank[N_EXP];
#pragma unroll
    for (int e = 0; e < N_EXP; ++e) {
        unsigned long long bal = __ballot((m8 >> e) & 1u);
        lrank[e] = __popcll(bal & ((1ull << lane) - 1ull));
        if (lane == 0) wcnt[wave][e] = __popcll(bal);
    }
    __syncthreads();
    if (threadIdx.x < N_EXP) {
        int e = threadIdx.x; int a = 0;
        for (int wv = 0; wv < 4; ++wv) { wbase[wv][e] = a; a += wcnt[wv][e]; }
        bh[b * N_EXP + e] = a;
    }
    __syncthreads();
#pragma unroll
    for (int k = 0; k < TOP_K; ++k) {
        int e = topi[t * TOP_K + k];
        pose[t * TOP_K + k] = wbase[wave][e] + lrank[e];
    }
}

__global__ void scan16(const int* __restrict__ bh, int* __restrict__ bb,
                       int* __restrict__ off)
{
    __shared__ int tot[N_EXP];
    if (threadIdx.x < N_EXP) {
        int e = threadIdx.x; int a = 0;
        for (int b = 0; b < 16; ++b) { bb[b * N_EXP + e] = a; a += bh[b * N_EXP + e]; }
        tot[e] = a;
    }
    __syncthreads();
    if (threadIdx.x == 0) {
        int a = 0; off[0] = 0;
        for (int e = 0; e < N_EXP; ++e) { a += tot[e]; off[e + 1] = a; }
    }
}

__global__ __launch_bounds__(256)
void rank_final(const int* __restrict__ topi, const int* __restrict__ pose,
                const int* __restrict__ bb, const int* __restrict__ off,
                int* __restrict__ perm, int* __restrict__ slot_of)
{
    const int b = blockIdx.x;
    const int t = b * 256 + threadIdx.x;
#pragma unroll
    for (int k = 0; k < TOP_K; ++k) {
        int e = topi[t * TOP_K + k];
        int slot = off[e] + bb[b * N_EXP + e] + pose[t * TOP_K + k];
        perm[slot] = t;
        slot_of[t * TOP_K + k] = slot;
    }
}

template<bool YB>
__global__ __launch_bounds__(256)
void combine_k(const void* __restrict__ yv, const float* __restrict__ topw,
               const int* __restrict__ slot_of, float* __restrict__ h2,
               __bf16* __restrict__ h2b)
{
    int t = blockIdx.x;
    int64_t s[TOP_K]; float wgt[TOP_K];
#pragma unroll
    for (int k = 0; k < TOP_K; ++k) {
        s[k] = slot_of[t * TOP_K + k];
        wgt[k] = topw[t * TOP_K + k];
    }
    int64_t base4 = ((int64_t)t * D_MODEL) / 4 + threadIdx.x;
    float4 v = reinterpret_cast<const float4*>(h2)[base4];
#pragma unroll
    for (int k = 0; k < TOP_K; ++k) {
        float yy[4];
        if (YB) {
            bf16x4 yb = reinterpret_cast<const bf16x4*>((const __bf16*)yv)
                            [s[k] * (D_MODEL / 4) + threadIdx.x];
            yy[0] = (float)yb[0]; yy[1] = (float)yb[1];
            yy[2] = (float)yb[2]; yy[3] = (float)yb[3];
        } else {
            float4 yf = reinterpret_cast<const float4*>((const float*)yv)
                            [s[k] * (D_MODEL / 4) + threadIdx.x];
            yy[0] = yf.x; yy[1] = yf.y; yy[2] = yf.z; yy[3] = yf.w;
        }
        v.x = fmaf(wgt[k], yy[0], v.x);
        v.y = fmaf(wgt[k], yy[1], v.y);
        v.z = fmaf(wgt[k], yy[2], v.z);
        v.w = fmaf(wgt[k], yy[3], v.w);
    }
    if (h2b) {
        bf16x4 o;
        o[0] = (__bf16)v.x; o[1] = (__bf16)v.y;
        o[2] = (__bf16)v.z; o[3] = (__bf16)v.w;
        reinterpret_cast<bf16x4*>(h2b)[base4] = o;
    } else {
        reinterpret_cast<float4*>(h2)[base4] = v;
    }
}

// -------------------------------------------------------------------------
extern "C" void kernel_launch(void* const* d_in, const int* in_sizes, int n_in,
                              void* d_out, int out_size, void* d_ws, size_t ws_size,
                              hipStream_t stream)
{
    const float* x      = (const float*)d_in[0];
    const float* lin0_w = (const float*)d_in[1];
    const float* lin0_b = (const float*)d_in[2];
    const float* s1w1   = (const float*)d_in[3];
    const float* s1b1   = (const float*)d_in[4];
    const float* s1w2   = (const float*)d_in[5];
    const float* s1b2   = (const float*)d_in[6];
    const float* gate_w = (const float*)d_in[7];
    const float* ew1    = (const float*)d_in[8];
    const float* ew3    = (const float*)d_in[9];
    const float* ew2    = (const float*)d_in[10];
    const float* shw1   = (const float*)d_in[11];
    const float* shw3   = (const float*)d_in[12];
    const float* shw2   = (const float*)d_in[13];
    const float* lin1_w = (const float*)d_in[14];
    const float* lin1_b = (const float*)d_in[15];
    const float* s2w1   = (const float*)d_in[16];
    const float* s2b1   = (const float*)d_in[17];
    const float* s2w2   = (const float*)d_in[18];
    const float* s2b2   = (const float*)d_in[19];
    float* out = (float*)d_out;

    char* ws = (char*)d_ws;
    const size_t MB = 1024 * 1024;
    dim3 blk(256);
    const int64_t ES = (int64_t)D_MODEL * H_EXP;
    const bool full = ws_size >= (size_t)216 * MB;

    if (full) {
        // ---- round-10 proven arena ----
        float*  h0 = (float*)(ws + 0 * MB);
        float*  h1 = (float*)(ws + 16 * MB);
        float*  h2 = (float*)(ws + 32 * MB);
        __bf16* yexp_b = (__bf16*)(ws + 48 * MB);
        __bf16* gu_b   = (__bf16*)(ws + 80 * MB);
        __bf16* gsh_b  = gu_b;
        __bf16* h1b = (__bf16*)(ws + 112 * MB);
        __bf16* h2b = (__bf16*)(ws + 120 * MB);
        __bf16* h3b = (__bf16*)(ws + 128 * MB);
        __bf16* e1T = (__bf16*)(ws + 136 * MB);
        __bf16* e3T = (__bf16*)(ws + 152 * MB);
        __bf16* e2T = (__bf16*)(ws + 168 * MB);
        __bf16* s1T = (__bf16*)(ws + 184 * MB);
        __bf16* s3T = (__bf16*)(ws + 188 * MB);
        __bf16* s2T = (__bf16*)(ws + 192 * MB);
        __bf16* l1T = (__bf16*)(ws + 196 * MB);
        __bf16* q1T = (__bf16*)(ws + 198 * MB);
        __bf16* q2T = (__bf16*)(ws + 200 * MB);
        char* sm = ws + 202 * MB;
        int*   topi    = (int*)(sm);
        float* topw    = (float*)(sm + 64 * 1024);
        int*   pose    = (int*)(sm + 128 * 1024);
        int*   slot_of = (int*)(sm + 192 * 1024);
        int*   perm    = (int*)(sm + 256 * 1024);
        int*   bh      = (int*)(sm + 320 * 1024);
        int*   bb      = (int*)(sm + 321 * 1024);
        int*   off     = (int*)(sm + 322 * 1024);
        unsigned char* emask = (unsigned char*)(sm + 323 * 1024);

        // 0. weight transpose+convert (RNE)
        f2bT<<<dim3(32, 32, N_EXP), blk, 0, stream>>>(ew1, e1T, D_MODEL, H_EXP);
        f2bT<<<dim3(32, 32, N_EXP), blk, 0, stream>>>(ew3, e3T, D_MODEL, H_EXP);
        f2bT<<<dim3(32, 32, N_EXP), blk, 0, stream>>>(ew2, e2T, H_EXP, D_MODEL);
        f2bT<<<dim3(64, 32, 1), blk, 0, stream>>>(shw1, s1T, D_MODEL, SH_HID);
        f2bT<<<dim3(64, 32, 1), blk, 0, stream>>>(shw3, s3T, D_MODEL, SH_HID);
        f2bT<<<dim3(32, 64, 1), blk, 0, stream>>>(shw2, s2T, SH_HID, D_MODEL);
        f2bT<<<dim3(32, 32, 1), blk, 0, stream>>>(lin1_w, l1T, D_MODEL, D_MODEL);
        f2bT<<<dim3(32, 32, 1), blk, 0, stream>>>(s2w1, q1T, D_MODEL, D_MODEL);
        f2bT<<<dim3(32, 32, 1), blk, 0, stream>>>(s2w2, q2T, D_MODEL, D_MODEL);

        // 1. lin0 (split3, router prefix)
        gemm_sp<3, false, false, false><<<dim3(8, 32, 1), blk, 0, stream>>>(
            x, D_MODEL, lin0_w, nullptr, 0, D_MODEL, lin0_b, nullptr,
            h0, nullptr, D_MODEL, T_TOKENS, D_MODEL, nullptr, nullptr);

        // 2. swi1 fused-GLU (split3) -> h1 fp32 + h1b bf16
        gemm_sp<3, false, false, true><<<dim3(16, 32, 1), blk, 0, stream>>>(
            h0, D_MODEL, s1w1, s1w2, 0, D_MODEL, s1b1, s1b2,
            h1, h1b, D_MODEL, T_TOKENS, D_MODEL, nullptr, nullptr);

        // 3. router
        router_logits<<<T_TOKENS / 4, blk, 0, stream>>>(h1, gate_w, topi, topw, emask);
        rank_local<<<16, blk, 0, stream>>>(emask, topi, pose, bh);
        scan16<<<1, 64, 0, stream>>>(bh, bb, off);
        rank_final<<<16, blk, 0, stream>>>(topi, pose, bb, off, perm, slot_of);

        // 4. expA GLU -> gu_b   (BK=64: half the barriers)
        gemm_b64<true, true, true, true><<<dim3(16, 128, N_EXP), blk, 0, stream>>>(
            h1b, D_MODEL, e1T, e3T, ES, D_MODEL, nullptr, nullptr,
            nullptr, gu_b, H_EXP, 0, D_MODEL, off, perm);
        // 5. expB -> yexp_b
        gemm_b64<true, false, false, true><<<dim3(8, 128, N_EXP), blk, 0, stream>>>(
            gu_b, H_EXP, e2T, nullptr, ES, H_EXP, nullptr, nullptr,
            nullptr, yexp_b, D_MODEL, 0, H_EXP, off, nullptr);
        // 6. shA GLU -> gsh_b (aliases gu_b, dead)
        gemm_b64<false, false, true, true><<<dim3(32, 32, 1), blk, 0, stream>>>(
            h1b, D_MODEL, s1T, s3T, 0, D_MODEL, nullptr, nullptr,
            nullptr, gsh_b, SH_HID, T_TOKENS, D_MODEL, nullptr, nullptr);
        // 7. shB -> h2 fp32
        gemm_b64<false, false, false, false><<<dim3(8, 32, 1), blk, 0, stream>>>(
            gsh_b, SH_HID, s2T, nullptr, 0, SH_HID, nullptr, nullptr,
            h2, nullptr, D_MODEL, T_TOKENS, SH_HID, nullptr, nullptr);

        // 8. combine -> h2b
        combine_k<true><<<T_TOKENS, blk, 0, stream>>>(yexp_b, topw, slot_of, h2, h2b);

        // 9. lin1 (bf16, +bias) -> h3b
        gemm_b64<false, false, false, true><<<dim3(8, 32, 1), blk, 0, stream>>>(
            h2b, D_MODEL, l1T, nullptr, 0, D_MODEL, lin1_b, nullptr,
            nullptr, h3b, D_MODEL, T_TOKENS, D_MODEL, nullptr, nullptr);

        // 10. swi2 fused-GLU (bf16, +biases) -> out fp32
        gemm_b64<false, false, true, false><<<dim3(16, 32, 1), blk, 0, stream>>>(
            h3b, D_MODEL, q1T, q2T, 0, D_MODEL, s2b1, s2b2,
            out, nullptr, D_MODEL, T_TOKENS, D_MODEL, nullptr, nullptr);
    } else {
        // ---- fallback (round-10 proven, <216 MB) ----
        float* h0 = (float*)(ws + 0 * MB);
        float* h1 = (float*)(ws + 16 * MB);
        float* h2 = (float*)(ws + 32 * MB);
        float* yexp  = (float*)(ws + 48 * MB);
        __bf16* gu_b = (__bf16*)(ws + 112 * MB);
        __bf16* gsh_b = gu_b;
        __bf16* h1b  = (__bf16*)(ws + 144 * MB);
        char* sm = ws + 152 * MB;
        int*   topi    = (int*)(sm);
        float* topw    = (float*)(sm + 64 * 1024);
        int*   pose    = (int*)(sm + 128 * 1024);
        int*   slot_of = (int*)(sm + 192 * 1024);
        int*   perm    = (int*)(sm + 256 * 1024);
        int*   bh      = (int*)(sm + 320 * 1024);
        int*   bb      = (int*)(sm + 321 * 1024);
        int*   off     = (int*)(sm + 322 * 1024);
        unsigned char* emask = (unsigned char*)(sm + 323 * 1024);

        gemm_sp<3, false, false, false><<<dim3(8, 32, 1), blk, 0, stream>>>(
            x, D_MODEL, lin0_w, nullptr, 0, D_MODEL, lin0_b, nullptr,
            h0, nullptr, D_MODEL, T_TOKENS, D_MODEL, nullptr, nullptr);
        gemm_sp<3, false, false, true><<<dim3(16, 32, 1), blk, 0, stream>>>(
            h0, D_MODEL, s1w1, s1w2, 0, D_MODEL, s1b1, s1b2,
            h1, h1b, D_MODEL, T_TOKENS, D_MODEL, nullptr, nullptr);

        router_logits<<<T_TOKENS / 4, blk, 0, stream>>>(h1, gate_w, topi, topw, emask);
        rank_local<<<16, blk, 0, stream>>>(emask, topi, pose, bh);
        scan16<<<1, 64, 0, stream>>>(bh, bb, off);
        rank_final<<<16, blk, 0, stream>>>(topi, pose, bb, off, perm, slot_of);

        gemm_bb<false, true, true, true, true><<<dim3(16, 128, N_EXP), blk, 0, stream>>>(
            h1b, D_MODEL, ew1, ew3, ES, H_EXP, nullptr, nullptr,
            nullptr, gu_b, H_EXP, 0, D_MODEL, off, perm);
        gemm_bb<false, true, false, false, false><<<dim3(8, 128, N_EXP), blk, 0, stream>>>(
            gu_b, H_EXP, ew2, nullptr, (int64_t)H_EXP * D_MODEL, D_MODEL, nullptr, nullptr,
            yexp, nullptr, D_MODEL, 0, H_EXP, off, nullptr);
        gemm_bb<false, false, false, true, true><<<dim3(32, 32, 1), blk, 0, stream>>>(
            h1b, D_MODEL, shw1, shw3, 0, SH_HID, nullptr, nullptr,
            nullptr, gsh_b, SH_HID, T_TOKENS, D_MODEL, nullptr, nullptr);
        gemm_bb<false, false, false, false, false><<<dim3(8, 32, 1), blk, 0, stream>>>(
            gsh_b, SH_HID, shw2, nullptr, 0, D_MODEL, nullptr, nullptr,
            h2, nullptr, D_MODEL, T_TOKENS, SH_HID, nullptr, nullptr);

        combine_k<false><<<T_TOKENS, blk, 0, stream>>>(yexp, topw, slot_of, h2, nullptr);

        gemm_sp<2, false, false, false><<<dim3(8, 32, 1), blk, 0, stream>>>(
            h2, D_MODEL, lin1_w, nullptr, 0, D_MODEL, lin1_b, nullptr,
            h0, nullptr, D_MODEL, T_TOKENS, D_MODEL, nullptr, nullptr);
        gemm_sp<2, false, false, true><<<dim3(16, 32, 1), blk, 0, stream>>>(
            h0, D_MODEL, s2w1, s2w2, 0, D_MODEL, s2b1, s2b2,
            out, nullptr, D_MODEL, T_TOKENS, D_MODEL, nullptr, nullptr);
    }
}